// Round 1
// baseline (177.832 us; speedup 1.0000x reference)
//
#include <hip/hip_runtime.h>

#define HW 16384   // H*W
#define NH 4
#define HD 16

// ---------------- Kernel 1: QKV projection ----------------
// x: (B,64,HW) f32.  w: (192,64). bias: (192,)
// Outputs qT,kT,vT: layout [((b*4+h)*HW + p)*16 + d], q pre-scaled by 0.25.
__global__ __launch_bounds__(256) void qkv_kernel(
    const float* __restrict__ x, const float* __restrict__ w,
    const float* __restrict__ bias, float* __restrict__ qT,
    float* __restrict__ kT, float* __restrict__ vT)
{
  int blk = blockIdx.x;            // 512 blocks: 256 strips per batch
  int b   = blk >> 8;
  int p0  = (blk & 255) * 64;
  int t   = threadIdx.x;
  int px  = t & 63;
  int og  = t >> 6;                // 0..3, wave-uniform
  int p   = p0 + px;

  const float* xp = x + (size_t)b * 64 * HW + p;
  float xr[64];
#pragma unroll
  for (int c = 0; c < 64; ++c) xr[c] = xp[(size_t)c * HW];

  // each og handles 48 outputs = 3 aligned quads of 16
  for (int q16 = 0; q16 < 3; ++q16) {
    int o0   = og * 48 + q16 * 16;     // multiple of 16
    int tsel = o0 >> 6;                // 0=q,1=k,2=v (wave-uniform)
    int h    = (o0 >> 4) & 3;
    float acc[16];
#pragma unroll
    for (int d = 0; d < 16; ++d) {
      const float* wr = w + (o0 + d) * 64;
      float a = 0.f;
#pragma unroll
      for (int c = 0; c < 64; ++c) a += wr[c] * xr[c];
      acc[d] = a + bias[o0 + d];
    }
    if (tsel == 0) {
#pragma unroll
      for (int d = 0; d < 16; ++d) acc[d] *= 0.25f;   // hd^-0.5
    }
    float* dst = (tsel == 0) ? qT : ((tsel == 1) ? kT : vT);
    float4* dp = (float4*)(dst + ((size_t)(b * NH + h) * HW + p) * HD);
    dp[0] = make_float4(acc[0], acc[1], acc[2], acc[3]);
    dp[1] = make_float4(acc[4], acc[5], acc[6], acc[7]);
    dp[2] = make_float4(acc[8], acc[9], acc[10], acc[11]);
    dp[3] = make_float4(acc[12], acc[13], acc[14], acc[15]);
  }
}

// ---------------- Kernel 2: fused neighborhood attention + output proj -------
// Block: 64 consecutive pixels x 4 heads (one head per wave).
__global__ __launch_bounds__(256) void attn_kernel(
    const float* __restrict__ qT, const float* __restrict__ kT,
    const float* __restrict__ vT, const float* __restrict__ rb,
    const float* __restrict__ pw, const float* __restrict__ pb,
    float* __restrict__ out)
{
  __shared__ float att[64][65];

  int blk = blockIdx.x;            // 512
  int b   = blk >> 8;
  int p0  = (blk & 255) * 64;
  int t   = threadIdx.x;
  int px  = t & 63;
  int h   = t >> 6;                // wave-uniform
  int n   = p0 + px;
  int y   = n >> 7, xc = n & 127;
  int sy  = y - 3; sy = sy < 0 ? 0 : (sy > 121 ? 121 : sy);
  int sx  = xc - 3; sx = sx < 0 ? 0 : (sx > 121 ? 121 : sx);
  int ih  = y - sy, iw = xc - sx;

  size_t base = (size_t)(b * NH + h) * HW;
  const float4* qp = (const float4*)(qT + (base + n) * HD);
  float4 q0 = qp[0], q1 = qp[1], q2 = qp[2], q3 = qp[3];

  float lg[49];
#pragma unroll
  for (int i = 0; i < 7; ++i) {
#pragma unroll
    for (int j = 0; j < 7; ++j) {
      const float4* kp =
          (const float4*)(kT + (base + (size_t)(sy + i) * 128 + sx + j) * HD);
      float4 k0 = kp[0], k1 = kp[1], k2 = kp[2], k3 = kp[3];
      float d = q0.x*k0.x + q0.y*k0.y + q0.z*k0.z + q0.w*k0.w
              + q1.x*k1.x + q1.y*k1.y + q1.z*k1.z + q1.w*k1.w
              + q2.x*k2.x + q2.y*k2.y + q2.z*k2.z + q2.w*k2.w
              + q3.x*k3.x + q3.y*k3.y + q3.z*k3.z + q3.w*k3.w;
      lg[i * 7 + j] = d + rb[((ih + i) * 13 + (iw + j)) * NH + h];
    }
  }

  float mx = lg[0];
#pragma unroll
  for (int k = 1; k < 49; ++k) mx = fmaxf(mx, lg[k]);
  float s = 0.f;
#pragma unroll
  for (int k = 0; k < 49; ++k) { lg[k] = __expf(lg[k] - mx); s += lg[k]; }
  float inv = 1.f / s;

  float4 o0 = make_float4(0,0,0,0), o1 = o0, o2 = o0, o3 = o0;
#pragma unroll
  for (int i = 0; i < 7; ++i) {
#pragma unroll
    for (int j = 0; j < 7; ++j) {
      const float4* vp =
          (const float4*)(vT + (base + (size_t)(sy + i) * 128 + sx + j) * HD);
      float4 v0 = vp[0], v1 = vp[1], v2 = vp[2], v3 = vp[3];
      float p = lg[i * 7 + j];
      o0.x += p * v0.x; o0.y += p * v0.y; o0.z += p * v0.z; o0.w += p * v0.w;
      o1.x += p * v1.x; o1.y += p * v1.y; o1.z += p * v1.z; o1.w += p * v1.w;
      o2.x += p * v2.x; o2.y += p * v2.y; o2.z += p * v2.z; o2.w += p * v2.w;
      o3.x += p * v3.x; o3.y += p * v3.y; o3.z += p * v3.z; o3.w += p * v3.w;
    }
  }

  int hc = h * 16;
  att[hc + 0][px] = o0.x * inv;  att[hc + 1][px] = o0.y * inv;
  att[hc + 2][px] = o0.z * inv;  att[hc + 3][px] = o0.w * inv;
  att[hc + 4][px] = o1.x * inv;  att[hc + 5][px] = o1.y * inv;
  att[hc + 6][px] = o1.z * inv;  att[hc + 7][px] = o1.w * inv;
  att[hc + 8][px] = o2.x * inv;  att[hc + 9][px] = o2.y * inv;
  att[hc +10][px] = o2.z * inv;  att[hc +11][px] = o2.w * inv;
  att[hc +12][px] = o3.x * inv;  att[hc +13][px] = o3.y * inv;
  att[hc +14][px] = o3.z * inv;  att[hc +15][px] = o3.w * inv;

  __syncthreads();

  // ---- phase B: 64x64 output projection ----
  int og = t >> 6;                 // wave-uniform
  float acc[16];
#pragma unroll
  for (int oo = 0; oo < 16; ++oo) acc[oo] = pb[og * 16 + oo];
  for (int c = 0; c < 64; ++c) {
    float a = att[c][px];
#pragma unroll
    for (int oo = 0; oo < 16; ++oo)
      acc[oo] += pw[(og * 16 + oo) * 64 + c] * a;
  }
#pragma unroll
  for (int oo = 0; oo < 16; ++oo)
    out[((size_t)b * 64 + og * 16 + oo) * HW + n] = acc[oo];
}

extern "C" void kernel_launch(void* const* d_in, const int* in_sizes, int n_in,
                              void* d_out, int out_size, void* d_ws, size_t ws_size,
                              hipStream_t stream) {
  const float* x      = (const float*)d_in[0];
  const float* qkv_w  = (const float*)d_in[1];
  const float* qkv_b  = (const float*)d_in[2];
  const float* proj_w = (const float*)d_in[3];
  const float* proj_b = (const float*)d_in[4];
  const float* rb     = (const float*)d_in[5];
  float* out = (float*)d_out;

  const size_t TSZ = (size_t)2 * NH * HW * HD;   // 2,097,152 floats each
  float* qT = (float*)d_ws;
  float* kT = qT + TSZ;
  float* vT = kT + TSZ;

  qkv_kernel<<<512, 256, 0, stream>>>(x, qkv_w, qkv_b, qT, kT, vT);
  attn_kernel<<<512, 256, 0, stream>>>(qT, kT, vT, rb, proj_w, proj_b, out);
}

// Round 2
// 121.525 us; speedup vs baseline: 1.4633x; 1.4633x over previous
//
#include <hip/hip_runtime.h>

#define HW 16384   // H*W
#define NH 4
#define HD 16

// ---------------- Kernel 1: QKV projection (LDS-staged, 12-way output split) --
// grid: dim3(3, 256, 2) = (slice, strip, batch); block 256 = 64px x 4 osub
// Outputs qT,kT,vT: layout [((b*4+h)*HW + p)*16 + d], q pre-scaled by 0.25.
__global__ __launch_bounds__(256) void qkv_kernel(
    const float* __restrict__ x, const float* __restrict__ w,
    const float* __restrict__ bias, float* __restrict__ qT,
    float* __restrict__ kT, float* __restrict__ vT)
{
  __shared__ float xs[64][64];
  int slice = blockIdx.x;          // 0..2
  int p0    = blockIdx.y * 64;
  int b     = blockIdx.z;
  int t     = threadIdx.x;

  {  // stage x strip [64ch][64px]
    int c = t >> 2, f4 = t & 3;
    const float4* src = (const float4*)(x + (size_t)(b * 64 + c) * HW + p0);
    float4* dst = (float4*)(&xs[c][0]);
#pragma unroll
    for (int k2 = 0; k2 < 4; ++k2) dst[f4 * 4 + k2] = src[f4 * 4 + k2];
  }
  __syncthreads();

  int px  = t & 63;
  int o16 = slice * 4 + (t >> 6);  // 0..11, wave-uniform
  int o0  = o16 * 16;
  int tsel = o16 >> 2;             // 0=q,1=k,2=v
  int h    = o16 & 3;

  float acc[16];
#pragma unroll
  for (int d = 0; d < 16; ++d) acc[d] = bias[o0 + d];
  for (int c = 0; c < 64; ++c) {
    float a = xs[c][px];
#pragma unroll
    for (int d = 0; d < 16; ++d) acc[d] = fmaf(w[(o0 + d) * 64 + c], a, acc[d]);
  }
  if (tsel == 0) {
#pragma unroll
    for (int d = 0; d < 16; ++d) acc[d] *= 0.25f;   // hd^-0.5
  }
  float* dst = (tsel == 0) ? qT : ((tsel == 1) ? kT : vT);
  float4* dp = (float4*)(dst + ((size_t)(b * NH + h) * HW + p0 + px) * HD);
  dp[0] = make_float4(acc[0], acc[1], acc[2], acc[3]);
  dp[1] = make_float4(acc[4], acc[5], acc[6], acc[7]);
  dp[2] = make_float4(acc[8], acc[9], acc[10], acc[11]);
  dp[3] = make_float4(acc[12], acc[13], acc[14], acc[15]);
}

// ---------------- Kernel 2: tiled neighborhood attention (LDS halos) ---------
// grid: dim3(64, 4, 2) = (tile, head, batch); block 256 = 16x16 pixel tile.
// Writes attention output (pre-proj) channel-major into d_out: [(b*64+h*16+d)][p]
__global__ __launch_bounds__(256) void attn_kernel(
    const float* __restrict__ qT, const float* __restrict__ kT,
    const float* __restrict__ vT, const float* __restrict__ rb,
    float* __restrict__ attO)
{
  __shared__ float Kl[16][22][22];
  __shared__ float Vl[16][22][22];
  __shared__ float rbl[169];

  int tile = blockIdx.x;           // 0..63 (8x8 tiles of 16x16)
  int h    = blockIdx.y;
  int b    = blockIdx.z;
  int tx0  = (tile & 7) * 16;
  int ty0  = (tile >> 3) * 16;
  int oy   = ty0 - 3, ox = tx0 - 3;   // halo origin (may be negative)
  int t    = threadIdx.x;

  size_t base = (size_t)(b * NH + h) * HW;

  if (t < 169) rbl[t] = rb[t * NH + h];

  // stage K and V halos: 484 px * 4 float4 = 1936 items each
  for (int idx = t; idx < 1936; idx += 256) {
    int pxi = idx >> 2, d4 = idx & 3;
    int r = pxi / 22, c = pxi % 22;
    int ra = oy + r; ra = ra < 0 ? 0 : (ra > 127 ? 127 : ra);
    int ca = ox + c; ca = ca < 0 ? 0 : (ca > 127 ? 127 : ca);
    size_t gp = (base + (size_t)ra * 128 + ca) * HD;
    float4 kv = ((const float4*)(kT + gp))[d4];
    float4 vv = ((const float4*)(vT + gp))[d4];
    int dd = d4 * 4;
    Kl[dd + 0][r][c] = kv.x; Kl[dd + 1][r][c] = kv.y;
    Kl[dd + 2][r][c] = kv.z; Kl[dd + 3][r][c] = kv.w;
    Vl[dd + 0][r][c] = vv.x; Vl[dd + 1][r][c] = vv.y;
    Vl[dd + 2][r][c] = vv.z; Vl[dd + 3][r][c] = vv.w;
  }

  int lx = t & 15, ly = t >> 4;
  int y = ty0 + ly, xc = tx0 + lx;
  int sy = y - 3;  sy = sy < 0 ? 0 : (sy > 121 ? 121 : sy);
  int sx = xc - 3; sx = sx < 0 ? 0 : (sx > 121 ? 121 : sx);
  int li0 = sy - oy, lj0 = sx - ox;      // local window origin in halo
  int ih = y - sy, iw = xc - sx;         // bias offsets

  float qd[16];
  {
    const float4* qp = (const float4*)(qT + (base + (size_t)y * 128 + xc) * HD);
#pragma unroll
    for (int k = 0; k < 4; ++k) {
      float4 v = qp[k];
      qd[4 * k + 0] = v.x; qd[4 * k + 1] = v.y;
      qd[4 * k + 2] = v.z; qd[4 * k + 3] = v.w;
    }
  }

  __syncthreads();

  float lg[49];
#pragma unroll
  for (int i = 0; i < 7; ++i) {
#pragma unroll
    for (int j = 0; j < 7; ++j) {
      int r = li0 + i, c = lj0 + j;
      float d = 0.f;
#pragma unroll
      for (int dd = 0; dd < 16; ++dd) d = fmaf(qd[dd], Kl[dd][r][c], d);
      lg[i * 7 + j] = d + rbl[(ih + i) * 13 + (iw + j)];
    }
  }

  float mx = lg[0];
#pragma unroll
  for (int k = 1; k < 49; ++k) mx = fmaxf(mx, lg[k]);
  float s = 0.f;
#pragma unroll
  for (int k = 0; k < 49; ++k) { lg[k] = __expf(lg[k] - mx); s += lg[k]; }
  float inv = 1.f / s;

  float o[16];
#pragma unroll
  for (int dd = 0; dd < 16; ++dd) o[dd] = 0.f;
#pragma unroll
  for (int i = 0; i < 7; ++i) {
#pragma unroll
    for (int j = 0; j < 7; ++j) {
      int r = li0 + i, c = lj0 + j;
      float p = lg[i * 7 + j];
#pragma unroll
      for (int dd = 0; dd < 16; ++dd) o[dd] = fmaf(p, Vl[dd][r][c], o[dd]);
    }
  }

  // write channel-major (pre-projection) into attO (= d_out, overwritten later)
  size_t op = (size_t)y * 128 + xc;
#pragma unroll
  for (int dd = 0; dd < 16; ++dd)
    attO[((size_t)b * 64 + h * 16 + dd) * HW + op] = o[dd] * inv;
}

// ---------------- Kernel 3: output projection (in-place over d_out) ----------
// grid: dim3(256, 2) = (strip, batch); block 256 = 64px x 4 og.
// Reads its own 64x64 strip of attO (=d_out) into LDS, syncs, overwrites it.
__global__ __launch_bounds__(256) void proj_kernel(
    const float* __restrict__ pw, const float* __restrict__ pb,
    float* __restrict__ out)
{
  __shared__ float as[64][64];
  int p0 = blockIdx.x * 64;
  int b  = blockIdx.y;
  int t  = threadIdx.x;

  {
    int c = t >> 2, f4 = t & 3;
    const float4* src = (const float4*)(out + (size_t)(b * 64 + c) * HW + p0);
    float4* dst = (float4*)(&as[c][0]);
#pragma unroll
    for (int k2 = 0; k2 < 4; ++k2) dst[f4 * 4 + k2] = src[f4 * 4 + k2];
  }
  __syncthreads();

  int px = t & 63, og = t >> 6;
  float acc[16];
#pragma unroll
  for (int oo = 0; oo < 16; ++oo) acc[oo] = pb[og * 16 + oo];
  for (int c = 0; c < 64; ++c) {
    float a = as[c][px];
#pragma unroll
    for (int oo = 0; oo < 16; ++oo)
      acc[oo] = fmaf(pw[(og * 16 + oo) * 64 + c], a, acc[oo]);
  }
#pragma unroll
  for (int oo = 0; oo < 16; ++oo)
    out[((size_t)b * 64 + og * 16 + oo) * HW + p0 + px] = acc[oo];
}

extern "C" void kernel_launch(void* const* d_in, const int* in_sizes, int n_in,
                              void* d_out, int out_size, void* d_ws, size_t ws_size,
                              hipStream_t stream) {
  const float* x      = (const float*)d_in[0];
  const float* qkv_w  = (const float*)d_in[1];
  const float* qkv_b  = (const float*)d_in[2];
  const float* proj_w = (const float*)d_in[3];
  const float* proj_b = (const float*)d_in[4];
  const float* rb     = (const float*)d_in[5];
  float* out = (float*)d_out;

  const size_t TSZ = (size_t)2 * NH * HW * HD;   // 2,097,152 floats each
  float* qT = (float*)d_ws;
  float* kT = qT + TSZ;
  float* vT = kT + TSZ;

  qkv_kernel<<<dim3(3, 256, 2), 256, 0, stream>>>(x, qkv_w, qkv_b, qT, kT, vT);
  attn_kernel<<<dim3(64, NH, 2), 256, 0, stream>>>(qT, kT, vT, rb, out);
  proj_kernel<<<dim3(256, 2), 256, 0, stream>>>(proj_w, proj_b, out);
}

// Round 3
// 67.506 us; speedup vs baseline: 2.6343x; 1.8002x over previous
//
#include <hip/hip_runtime.h>

#define HW 16384   // H*W
#define NH 4
#define HD 16

// ---------------- Kernel 1: QKV projection (LDS-staged x, SGPR weights) ------
// grid: dim3(3, 256, 2) = (slice, strip, batch); block 256 = 64px x 4 osub
// Outputs qT,kT,vT: layout [((b*4+h)*HW + p)*16 + d], q pre-scaled by 0.25.
__global__ __launch_bounds__(256) void qkv_kernel(
    const float* __restrict__ x, const float* __restrict__ w,
    const float* __restrict__ bias, float* __restrict__ qT,
    float* __restrict__ kT, float* __restrict__ vT)
{
  __shared__ float xs[64][72];     // pad 64->72 breaks write bank aliasing
  int slice = blockIdx.x;          // 0..2
  int p0    = blockIdx.y * 64;
  int b     = blockIdx.z;
  int t     = threadIdx.x;

  {  // stage x strip [64ch][64px]
    int c = t >> 2, f4 = t & 3;
    const float4* src = (const float4*)(x + (size_t)(b * 64 + c) * HW + p0);
    float4* dst = (float4*)(&xs[c][0]);
#pragma unroll
    for (int k2 = 0; k2 < 4; ++k2) dst[f4 * 4 + k2] = src[f4 * 4 + k2];
  }
  __syncthreads();

  int px = t & 63;
  // readfirstlane -> SGPR -> weight/bias addresses provably uniform -> s_load
  int wv  = __builtin_amdgcn_readfirstlane(t >> 6);
  int o16 = slice * 4 + wv;        // 0..11
  int o0  = o16 * 16;
  int tsel = o16 >> 2;             // 0=q,1=k,2=v
  int h    = o16 & 3;

  float acc[16];
#pragma unroll
  for (int d = 0; d < 16; ++d) acc[d] = bias[o0 + d];

  for (int c4 = 0; c4 < 16; ++c4) {
    float a0 = xs[c4 * 4 + 0][px];
    float a1 = xs[c4 * 4 + 1][px];
    float a2 = xs[c4 * 4 + 2][px];
    float a3 = xs[c4 * 4 + 3][px];
#pragma unroll
    for (int d = 0; d < 16; ++d) {
      const float* wr = w + (o0 + d) * 64 + c4 * 4;
      acc[d] = fmaf(wr[0], a0, acc[d]);
      acc[d] = fmaf(wr[1], a1, acc[d]);
      acc[d] = fmaf(wr[2], a2, acc[d]);
      acc[d] = fmaf(wr[3], a3, acc[d]);
    }
  }
  if (tsel == 0) {
#pragma unroll
    for (int d = 0; d < 16; ++d) acc[d] *= 0.25f;   // hd^-0.5
  }
  float* dst = (tsel == 0) ? qT : ((tsel == 1) ? kT : vT);
  float4* dp = (float4*)(dst + ((size_t)(b * NH + h) * HW + p0 + px) * HD);
  dp[0] = make_float4(acc[0], acc[1], acc[2], acc[3]);
  dp[1] = make_float4(acc[4], acc[5], acc[6], acc[7]);
  dp[2] = make_float4(acc[8], acc[9], acc[10], acc[11]);
  dp[3] = make_float4(acc[12], acc[13], acc[14], acc[15]);
}

// ---------------- Kernel 2: tiled neighborhood attention (LDS halos) ---------
// grid: dim3(64, 4, 2) = (tile, head, batch); block 256 = 16x16 pixel tile.
// Writes attention output (pre-proj) channel-major into d_out: [(b*64+h*16+d)][p]
__global__ __launch_bounds__(256) void attn_kernel(
    const float* __restrict__ qT, const float* __restrict__ kT,
    const float* __restrict__ vT, const float* __restrict__ rb,
    float* __restrict__ attO)
{
  __shared__ float Kl[16][22][22];
  __shared__ float Vl[16][22][22];
  __shared__ float rbl[169];

  int tile = blockIdx.x;           // 0..63 (8x8 tiles of 16x16)
  int h    = blockIdx.y;
  int b    = blockIdx.z;
  int tx0  = (tile & 7) * 16;
  int ty0  = (tile >> 3) * 16;
  int oy   = ty0 - 3, ox = tx0 - 3;   // halo origin (may be negative)
  int t    = threadIdx.x;

  size_t base = (size_t)(b * NH + h) * HW;

  if (t < 169) rbl[t] = rb[t * NH + h];

  // stage K and V halos: 484 px * 4 float4 = 1936 items each
  for (int idx = t; idx < 1936; idx += 256) {
    int pxi = idx >> 2, d4 = idx & 3;
    int r = pxi / 22, c = pxi % 22;
    int ra = oy + r; ra = ra < 0 ? 0 : (ra > 127 ? 127 : ra);
    int ca = ox + c; ca = ca < 0 ? 0 : (ca > 127 ? 127 : ca);
    size_t gp = (base + (size_t)ra * 128 + ca) * HD;
    float4 kv = ((const float4*)(kT + gp))[d4];
    float4 vv = ((const float4*)(vT + gp))[d4];
    int dd = d4 * 4;
    Kl[dd + 0][r][c] = kv.x; Kl[dd + 1][r][c] = kv.y;
    Kl[dd + 2][r][c] = kv.z; Kl[dd + 3][r][c] = kv.w;
    Vl[dd + 0][r][c] = vv.x; Vl[dd + 1][r][c] = vv.y;
    Vl[dd + 2][r][c] = vv.z; Vl[dd + 3][r][c] = vv.w;
  }

  int lx = t & 15, ly = t >> 4;
  int y = ty0 + ly, xc = tx0 + lx;
  int sy = y - 3;  sy = sy < 0 ? 0 : (sy > 121 ? 121 : sy);
  int sx = xc - 3; sx = sx < 0 ? 0 : (sx > 121 ? 121 : sx);
  int li0 = sy - oy, lj0 = sx - ox;      // local window origin in halo
  int ih = y - sy, iw = xc - sx;         // bias offsets

  float qd[16];
  {
    const float4* qp = (const float4*)(qT + (base + (size_t)y * 128 + xc) * HD);
#pragma unroll
    for (int k = 0; k < 4; ++k) {
      float4 v = qp[k];
      qd[4 * k + 0] = v.x; qd[4 * k + 1] = v.y;
      qd[4 * k + 2] = v.z; qd[4 * k + 3] = v.w;
    }
  }

  __syncthreads();

  float lg[49];
#pragma unroll
  for (int i = 0; i < 7; ++i) {
#pragma unroll
    for (int j = 0; j < 7; ++j) {
      int r = li0 + i, c = lj0 + j;
      float d = 0.f;
#pragma unroll
      for (int dd = 0; dd < 16; ++dd) d = fmaf(qd[dd], Kl[dd][r][c], d);
      lg[i * 7 + j] = d + rbl[(ih + i) * 13 + (iw + j)];
    }
  }

  float mx = lg[0];
#pragma unroll
  for (int k = 1; k < 49; ++k) mx = fmaxf(mx, lg[k]);
  float s = 0.f;
#pragma unroll
  for (int k = 0; k < 49; ++k) { lg[k] = __expf(lg[k] - mx); s += lg[k]; }
  float inv = 1.f / s;

  float o[16];
#pragma unroll
  for (int dd = 0; dd < 16; ++dd) o[dd] = 0.f;
#pragma unroll
  for (int i = 0; i < 7; ++i) {
#pragma unroll
    for (int j = 0; j < 7; ++j) {
      int r = li0 + i, c = lj0 + j;
      float p = lg[i * 7 + j];
#pragma unroll
      for (int dd = 0; dd < 16; ++dd) o[dd] = fmaf(p, Vl[dd][r][c], o[dd]);
    }
  }

  // write channel-major (pre-projection) into attO (= d_out, overwritten later)
  size_t op = (size_t)y * 128 + xc;
#pragma unroll
  for (int dd = 0; dd < 16; ++dd)
    attO[((size_t)b * 64 + h * 16 + dd) * HW + op] = o[dd] * inv;
}

// ---------------- Kernel 3: output projection (in-place over d_out) ----------
// grid: dim3(256, 2) = (strip, batch); block 256 = 64px x 4 og.
// Reads its own 64x64 strip of attO (=d_out) into LDS, syncs, overwrites it.
__global__ __launch_bounds__(256) void proj_kernel(
    const float* __restrict__ pw, const float* __restrict__ pb,
    float* __restrict__ out)
{
  __shared__ float as[64][72];
  int p0 = blockIdx.x * 64;
  int b  = blockIdx.y;
  int t  = threadIdx.x;

  {
    int c = t >> 2, f4 = t & 3;
    const float4* src = (const float4*)(out + (size_t)(b * 64 + c) * HW + p0);
    float4* dst = (float4*)(&as[c][0]);
#pragma unroll
    for (int k2 = 0; k2 < 4; ++k2) dst[f4 * 4 + k2] = src[f4 * 4 + k2];
  }
  __syncthreads();

  int px = t & 63;
  int og = __builtin_amdgcn_readfirstlane(t >> 6);   // uniform -> s_load weights
  float acc[16];
#pragma unroll
  for (int oo = 0; oo < 16; ++oo) acc[oo] = pb[og * 16 + oo];

  for (int c4 = 0; c4 < 16; ++c4) {
    float a0 = as[c4 * 4 + 0][px];
    float a1 = as[c4 * 4 + 1][px];
    float a2 = as[c4 * 4 + 2][px];
    float a3 = as[c4 * 4 + 3][px];
#pragma unroll
    for (int oo = 0; oo < 16; ++oo) {
      const float* wr = pw + (og * 16 + oo) * 64 + c4 * 4;
      acc[oo] = fmaf(wr[0], a0, acc[oo]);
      acc[oo] = fmaf(wr[1], a1, acc[oo]);
      acc[oo] = fmaf(wr[2], a2, acc[oo]);
      acc[oo] = fmaf(wr[3], a3, acc[oo]);
    }
  }
#pragma unroll
  for (int oo = 0; oo < 16; ++oo)
    out[((size_t)b * 64 + og * 16 + oo) * HW + p0 + px] = acc[oo];
}

extern "C" void kernel_launch(void* const* d_in, const int* in_sizes, int n_in,
                              void* d_out, int out_size, void* d_ws, size_t ws_size,
                              hipStream_t stream) {
  const float* x      = (const float*)d_in[0];
  const float* qkv_w  = (const float*)d_in[1];
  const float* qkv_b  = (const float*)d_in[2];
  const float* proj_w = (const float*)d_in[3];
  const float* proj_b = (const float*)d_in[4];
  const float* rb     = (const float*)d_in[5];
  float* out = (float*)d_out;

  const size_t TSZ = (size_t)2 * NH * HW * HD;   // 2,097,152 floats each
  float* qT = (float*)d_ws;
  float* kT = qT + TSZ;
  float* vT = kT + TSZ;

  qkv_kernel<<<dim3(3, 256, 2), 256, 0, stream>>>(x, qkv_w, qkv_b, qT, kT, vT);
  attn_kernel<<<dim3(64, NH, 2), 256, 0, stream>>>(qT, kT, vT, rb, out);
  proj_kernel<<<dim3(256, 2), 256, 0, stream>>>(proj_w, proj_b, out);
}